// Round 2
// baseline (580.224 us; speedup 1.0000x reference)
//
#include <hip/hip_runtime.h>
#include <math.h>

// Problem constants (HierarchicalAttention: WML=64, B=64, S=40, D=512)
#define BB   64
#define SS   40
#define WMLC 64
#define DD   512
#define NN   2560           // S*WML
#define NBLK 20             // chunks (blocks) per batch for the main pass
#define WPB  4              // waves per block
#define NWAVES (NBLK*WPB)   // 80 waves per batch
#define RPW (NN/NWAVES)     // 32 rows per wave
#define L2E 1.4426950408889634f

__device__ __forceinline__ float wave_reduce_sum(float v) {
    #pragma unroll
    for (int off = 32; off > 0; off >>= 1) v += __shfl_xor(v, off, 64);
    return v;
}

// ---------------------------------------------------------------------------
// K_PRE: one block per batch b.
//   qw[b,:] = src[b,:] @ W_word^T          (written to global for k_main)
//   qs      = src[b,:] @ W_sent^T          (stays in LDS)
//   sstat[b,s] = dot(qs, sent_bank[s,b,:]) * static_attn[b,s]
// W traffic: 2 MB/block x 64 blocks = 128 MB, L2-resident (~4 us aggregate).
// ---------------------------------------------------------------------------
__global__ __launch_bounds__(256) void k_pre(const float* __restrict__ src,
                                             const float* __restrict__ Ww,
                                             const float* __restrict__ Ws,
                                             const float* __restrict__ sb,
                                             const float* __restrict__ sa,
                                             float* __restrict__ qw,
                                             float* __restrict__ sstat) {
    __shared__ float xs[DD];
    __shared__ float qss[DD];
    const int b = blockIdx.x;
    const int t = threadIdx.x;
    ((float2*)xs)[t] = ((const float2*)(src + b * DD))[t];
    __syncthreads();

    // 4 dots of length 512 per thread: qw[t], qw[t+256], qs[t], qs[t+256]
    const float* ww0 = Ww + (size_t)t * DD;
    const float* ww1 = Ww + (size_t)(t + 256) * DD;
    const float* ws0 = Ws + (size_t)t * DD;
    const float* ws1 = Ws + (size_t)(t + 256) * DD;
    float aw0 = 0.f, aw1 = 0.f, as0 = 0.f, as1 = 0.f;
    for (int k = 0; k < DD; k += 4) {
        float4 x = *(const float4*)(xs + k);
        float4 w0 = *(const float4*)(ww0 + k);
        float4 w1 = *(const float4*)(ww1 + k);
        float4 s0 = *(const float4*)(ws0 + k);
        float4 s1 = *(const float4*)(ws1 + k);
        aw0 += x.x * w0.x + x.y * w0.y + x.z * w0.z + x.w * w0.w;
        aw1 += x.x * w1.x + x.y * w1.y + x.z * w1.z + x.w * w1.w;
        as0 += x.x * s0.x + x.y * s0.y + x.z * s0.z + x.w * s0.w;
        as1 += x.x * s1.x + x.y * s1.y + x.z * s1.z + x.w * s1.w;
    }
    qw[b * DD + t] = aw0;
    qw[b * DD + t + 256] = aw1;
    qss[t] = as0;
    qss[t + 256] = as1;
    __syncthreads();

    // sstat: 4 waves x 10 sentences
    const int wave = t >> 6, lane = t & 63;
    const int d0 = lane * 4, d1 = 256 + lane * 4;
    const float4 q0 = *(const float4*)(qss + d0);
    const float4 q1 = *(const float4*)(qss + d1);
    for (int j = 0; j < SS / WPB; ++j) {
        const int s = wave * (SS / WPB) + j;
        const float* row = sb + ((size_t)s * BB + b) * DD;
        float4 a0 = *(const float4*)(row + d0);
        float4 a1 = *(const float4*)(row + d1);
        float p = a0.x * q0.x + a0.y * q0.y + a0.z * q0.z + a0.w * q0.w
                + a1.x * q1.x + a1.y * q1.y + a1.z * q1.z + a1.w * q1.w;
        p = wave_reduce_sum(p);
        if (lane == 0) sstat[b * SS + s] = p * sa[b * SS + s];
    }
}

// ---------------------------------------------------------------------------
// K_MAIN (HBM-bound): streaming pass over VALID rows of word_bank only
// (~51% of 335 MB). One wave owns rows n = gw + 80k. Rows processed in
// PAIRS: two 2KB loads in flight + two interleaved shuffle-reduce chains
// per iteration (double the MLP / half the serial ds-permute exposure).
// Raw scores go straight into the d_out align region (finalized by k_post).
// ---------------------------------------------------------------------------
__global__ __launch_bounds__(256) void k_main(const float* __restrict__ wb,
                                              const float* __restrict__ qw,
                                              const float* __restrict__ sstat,
                                              const int* __restrict__ wl,
                                              float* __restrict__ scores,
                                              float* __restrict__ part_c,
                                              float* __restrict__ part_ml) {
    const int b = blockIdx.y;
    const int chunk = blockIdx.x;
    const int t = threadIdx.x, wave = t >> 6, lane = t & 63;
    const int gw = chunk * WPB + wave;               // 0..79
    const int d0 = lane * 4, d1 = 256 + lane * 4;
    const float4 q0 = *(const float4*)(qw + b * DD + d0);
    const float4 q1 = *(const float4*)(qw + b * DD + d1);

    float m = -INFINITY, l = 0.f;
    float4 c0 = {0.f, 0.f, 0.f, 0.f}, c1 = {0.f, 0.f, 0.f, 0.f};

    for (int k = 0; k < RPW; k += 2) {
        const int n0 = gw + k * NWAVES;
        const int n1 = n0 + NWAVES;
        const int s0 = n0 >> 6, w0 = n0 & 63;
        const int s1 = n1 >> 6, w1 = n1 & 63;
        const bool v0 = (w0 < wl[b * SS + s0]);
        const bool v1 = (w1 < wl[b * SS + s1]);
        float4 a00, a01, a10, a11;
        float p0 = 0.f, p1 = 0.f;
        const float* r0 = wb + (size_t)(((w0 * BB + b) * SS + s0)) * DD;
        const float* r1 = wb + (size_t)(((w1 * BB + b) * SS + s1)) * DD;
        if (v0) { a00 = *(const float4*)(r0 + d0); a01 = *(const float4*)(r0 + d1); }
        if (v1) { a10 = *(const float4*)(r1 + d0); a11 = *(const float4*)(r1 + d1); }
        if (v0) p0 = a00.x * q0.x + a00.y * q0.y + a00.z * q0.z + a00.w * q0.w
                   + a01.x * q1.x + a01.y * q1.y + a01.z * q1.z + a01.w * q1.w;
        if (v1) p1 = a10.x * q0.x + a10.y * q0.y + a10.z * q0.z + a10.w * q0.w
                   + a11.x * q1.x + a11.y * q1.y + a11.z * q1.z + a11.w * q1.w;
        #pragma unroll
        for (int off = 32; off > 0; off >>= 1) {      // two interleaved chains
            p0 += __shfl_xor(p0, off, 64);
            p1 += __shfl_xor(p1, off, 64);
        }
        if (v0) {
            const float a = p0 * sstat[b * SS + s0];
            if (lane == 0) scores[b * NN + n0] = a;
            if (a > m) {
                const float sc = (m == -INFINITY) ? 0.f : exp2f((m - a) * L2E);
                l *= sc;
                c0.x *= sc; c0.y *= sc; c0.z *= sc; c0.w *= sc;
                c1.x *= sc; c1.y *= sc; c1.z *= sc; c1.w *= sc;
                m = a;
            }
            const float e = exp2f((a - m) * L2E);
            l += e;
            c0.x += e * a00.x; c0.y += e * a00.y; c0.z += e * a00.z; c0.w += e * a00.w;
            c1.x += e * a01.x; c1.y += e * a01.y; c1.z += e * a01.z; c1.w += e * a01.w;
        }
        if (v1) {
            const float a = p1 * sstat[b * SS + s1];
            if (lane == 0) scores[b * NN + n1] = a;
            if (a > m) {
                const float sc = (m == -INFINITY) ? 0.f : exp2f((m - a) * L2E);
                l *= sc;
                c0.x *= sc; c0.y *= sc; c0.z *= sc; c0.w *= sc;
                c1.x *= sc; c1.y *= sc; c1.z *= sc; c1.w *= sc;
                m = a;
            }
            const float e = exp2f((a - m) * L2E);
            l += e;
            c0.x += e * a10.x; c0.y += e * a10.y; c0.z += e * a10.z; c0.w += e * a10.w;
            c1.x += e * a11.x; c1.y += e * a11.y; c1.z += e * a11.z; c1.w += e * a11.w;
        }
    }

    // intra-block combine of the 4 wave partials
    __shared__ float s_m[WPB], s_l[WPB];
    __shared__ float s_c[WPB][DD];
    *(float4*)(&s_c[wave][d0]) = c0;
    *(float4*)(&s_c[wave][d1]) = c1;
    if (lane == 0) { s_m[wave] = m; s_l[wave] = l; }
    __syncthreads();
    const float mb = fmaxf(fmaxf(s_m[0], s_m[1]), fmaxf(s_m[2], s_m[3]));
    float lb = 0.f, cA = 0.f, cB = 0.f;
    #pragma unroll
    for (int wv = 0; wv < WPB; ++wv) {
        const float mi = s_m[wv];
        const float sc = (mi == -INFINITY) ? 0.f : exp2f((mi - mb) * L2E);
        lb += s_l[wv] * sc;
        cA += s_c[wv][t] * sc;
        cB += s_c[wv][t + 256] * sc;
    }
    const int pidx = b * NBLK + chunk;
    part_c[(size_t)pidx * DD + t] = cA;
    part_c[(size_t)pidx * DD + t + 256] = cB;
    if (t == 0) { part_ml[pidx * 2] = mb; part_ml[pidx * 2 + 1] = lb; }
}

// ---------------------------------------------------------------------------
// K_POST: one block per batch b. Fuses partial-reduce + align finalize +
// attn_h. c_final and m/Z never touch global memory.
// ---------------------------------------------------------------------------
__global__ __launch_bounds__(256) void k_post(const float* __restrict__ part_c,
                                              const float* __restrict__ part_ml,
                                              const int* __restrict__ wl,
                                              const float* __restrict__ src,
                                              const float* __restrict__ Wout,
                                              float* __restrict__ out) {
    __shared__ float xs[2 * DD];     // concat(c_final, source)
    const int b = blockIdx.x, t = threadIdx.x;

    // global max over the 20 chunk partials (redundant per thread, L1-hot)
    float mg = -INFINITY;
    #pragma unroll
    for (int i = 0; i < NBLK; ++i) mg = fmaxf(mg, part_ml[(b * NBLK + i) * 2]);
    float Z = 0.f, cA = 0.f, cB = 0.f;
    for (int i = 0; i < NBLK; ++i) {
        const float mi = part_ml[(b * NBLK + i) * 2];
        const float li = part_ml[(b * NBLK + i) * 2 + 1];
        const float sc = (mi == -INFINITY) ? 0.f : exp2f((mi - mg) * L2E);
        Z += li * sc;
        cA += part_c[(size_t)(b * NBLK + i) * DD + t] * sc;
        cB += part_c[(size_t)(b * NBLK + i) * DD + t + 256] * sc;
    }
    const float invZ = 1.0f / Z;     // Z>0: every sentence has >=1 valid word
    xs[t] = cA * invZ;
    xs[t + 256] = cB * invZ;
    xs[DD + t] = src[b * DD + t];
    xs[DD + t + 256] = src[b * DD + t + 256];
    __syncthreads();

    // finalize align_vectors in place over the raw-score region of d_out
    float* av = out + BB * DD + (size_t)b * NN;
    #pragma unroll
    for (int j = 0; j < NN / 256; ++j) {
        const int n = j * 256 + t;
        const int s = n >> 6, w = n & 63;
        float v = 1e-20f;
        if (w < wl[b * SS + s]) v = exp2f((av[n] - mg) * L2E) * invZ + 1e-20f;
        av[n] = v;
    }

    // attn_h[b,d] = tanh( concat(c,src) . W_out[d,:] ), d = t and t+256
    #pragma unroll
    for (int rep = 0; rep < 2; ++rep) {
        const int d = rep * 256 + t;
        const float* row = Wout + (size_t)d * (2 * DD);
        float acc = 0.f;
        for (int k = 0; k < 2 * DD; k += 4) {
            float4 x = *(const float4*)(xs + k);
            float4 w = *(const float4*)(row + k);
            acc += x.x * w.x + x.y * w.y + x.z * w.z + x.w * w.w;
        }
        out[b * DD + d] = tanhf(acc);
    }
}

// ---------------------------------------------------------------------------
extern "C" void kernel_launch(void* const* d_in, const int* in_sizes, int n_in,
                              void* d_out, int out_size, void* d_ws, size_t ws_size,
                              hipStream_t stream) {
    const float* src = (const float*)d_in[0];   // [B, D]
    const float* wb  = (const float*)d_in[1];   // [WML, B, S, D]
    const int*   wl  = (const int*)  d_in[2];   // [B, S]
    const float* sb  = (const float*)d_in[3];   // [S, B, D]
    /* d_in[4] = sent_lengths: unused by forward math */
    const float* sa  = (const float*)d_in[5];   // [B, S]
    const float* Ww  = (const float*)d_in[6];   // [D, D]
    const float* Wsn = (const float*)d_in[7];   // [D, D]
    const float* Wo  = (const float*)d_in[8];   // [D, 2D]
    float* out = (float*)d_out;                 // [B*D] attn_h, then [B*N] align

    float* ws = (float*)d_ws;
    float* qw      = ws;                        // 32768
    float* sstat   = ws + 32768;                // 2560
    float* part_c  = ws + 35328;                // 64*20*512 = 655360
    float* part_ml = ws + 690688;               // 64*20*2   = 2560   (end ~2.8 MB)

    float* scores = out + BB * DD;              // raw scores live in the align slot

    hipLaunchKernelGGL(k_pre,  dim3(BB),       dim3(256), 0, stream, src, Ww, Wsn, sb, sa, qw, sstat);
    hipLaunchKernelGGL(k_main, dim3(NBLK, BB), dim3(256), 0, stream, wb, qw, sstat, wl,
                       scores, part_c, part_ml);
    hipLaunchKernelGGL(k_post, dim3(BB),       dim3(256), 0, stream, part_c, part_ml, wl, src, Wo, out);
}

// Round 3
// 576.678 us; speedup vs baseline: 1.0061x; 1.0061x over previous
//
#include <hip/hip_runtime.h>
#include <math.h>

// Problem constants (HierarchicalAttention: WML=64, B=64, S=40, D=512)
#define BB   64
#define SS   40
#define WMLC 64
#define DD   512
#define NN   2560           // S*WML
#define NBLK 20             // chunks (blocks) per batch for the main pass
#define WPB  4              // waves per block
#define NWAVES (NBLK*WPB)   // 80 waves per batch
#define RPW (NN/NWAVES)     // 32 rows per wave
#define L2E 1.4426950408889634f

__device__ __forceinline__ float wave_reduce_sum(float v) {
    #pragma unroll
    for (int off = 32; off > 0; off >>= 1) v += __shfl_xor(v, off, 64);
    return v;
}

// ---------------------------------------------------------------------------
// K_PRE: one block per batch b.
//   qw[b,:] = src[b,:] @ W_word^T          (written to global for k_main)
//   qs      = src[b,:] @ W_sent^T          (stays in LDS)
//   sstat[b,s] = dot(qs, sent_bank[s,b,:]) * static_attn[b,s]
// ---------------------------------------------------------------------------
__global__ __launch_bounds__(256) void k_pre(const float* __restrict__ src,
                                             const float* __restrict__ Ww,
                                             const float* __restrict__ Ws,
                                             const float* __restrict__ sb,
                                             const float* __restrict__ sa,
                                             float* __restrict__ qw,
                                             float* __restrict__ sstat) {
    __shared__ float xs[DD];
    __shared__ float qss[DD];
    const int b = blockIdx.x;
    const int t = threadIdx.x;
    ((float2*)xs)[t] = ((const float2*)(src + b * DD))[t];
    __syncthreads();

    // 4 dots of length 512 per thread: qw[t], qw[t+256], qs[t], qs[t+256]
    const float* ww0 = Ww + (size_t)t * DD;
    const float* ww1 = Ww + (size_t)(t + 256) * DD;
    const float* ws0 = Ws + (size_t)t * DD;
    const float* ws1 = Ws + (size_t)(t + 256) * DD;
    float aw0 = 0.f, aw1 = 0.f, as0 = 0.f, as1 = 0.f;
    for (int k = 0; k < DD; k += 4) {
        float4 x = *(const float4*)(xs + k);
        float4 w0 = *(const float4*)(ww0 + k);
        float4 w1 = *(const float4*)(ww1 + k);
        float4 s0 = *(const float4*)(ws0 + k);
        float4 s1 = *(const float4*)(ws1 + k);
        aw0 += x.x * w0.x + x.y * w0.y + x.z * w0.z + x.w * w0.w;
        aw1 += x.x * w1.x + x.y * w1.y + x.z * w1.z + x.w * w1.w;
        as0 += x.x * s0.x + x.y * s0.y + x.z * s0.z + x.w * s0.w;
        as1 += x.x * s1.x + x.y * s1.y + x.z * s1.z + x.w * s1.w;
    }
    qw[b * DD + t] = aw0;
    qw[b * DD + t + 256] = aw1;
    qss[t] = as0;
    qss[t + 256] = as1;
    __syncthreads();

    // sstat: 4 waves x 10 sentences
    const int wave = t >> 6, lane = t & 63;
    const int d0 = lane * 4, d1 = 256 + lane * 4;
    const float4 q0 = *(const float4*)(qss + d0);
    const float4 q1 = *(const float4*)(qss + d1);
    for (int j = 0; j < SS / WPB; ++j) {
        const int s = wave * (SS / WPB) + j;
        const float* row = sb + ((size_t)s * BB + b) * DD;
        float4 a0 = *(const float4*)(row + d0);
        float4 a1 = *(const float4*)(row + d1);
        float p = a0.x * q0.x + a0.y * q0.y + a0.z * q0.z + a0.w * q0.w
                + a1.x * q1.x + a1.y * q1.y + a1.z * q1.z + a1.w * q1.w;
        p = wave_reduce_sum(p);
        if (lane == 0) sstat[b * SS + s] = p * sa[b * SS + s];
    }
}

// ---------------------------------------------------------------------------
// K_MAIN (HBM-bound): R0's proven unpaired streaming loop. One wave owns
// rows n = gw + 80k (k<32) of batch b. Masked rows skipped entirely
// (wave-uniform `continue`, no load issued) — ~49% traffic saved.
// Raw scores go straight into the d_out align region (finalized by k_post).
// ---------------------------------------------------------------------------
__global__ __launch_bounds__(256) void k_main(const float* __restrict__ wb,
                                              const float* __restrict__ qw,
                                              const float* __restrict__ sstat,
                                              const int* __restrict__ wl,
                                              float* __restrict__ scores,
                                              float* __restrict__ part_c,
                                              float* __restrict__ part_ml) {
    const int b = blockIdx.y;
    const int chunk = blockIdx.x;
    const int t = threadIdx.x, wave = t >> 6, lane = t & 63;
    const int gw = chunk * WPB + wave;               // 0..79
    const int d0 = lane * 4, d1 = 256 + lane * 4;
    const float4 q0 = *(const float4*)(qw + b * DD + d0);
    const float4 q1 = *(const float4*)(qw + b * DD + d1);

    float m = -INFINITY, l = 0.f;
    float4 c0 = {0.f, 0.f, 0.f, 0.f}, c1 = {0.f, 0.f, 0.f, 0.f};

    for (int k = 0; k < RPW; ++k) {
        const int n = gw + k * NWAVES;
        const int s = n >> 6, w = n & 63;
        if (w >= wl[b * SS + s]) continue;           // wave-uniform skip
        const float* row = wb + (size_t)(((w * BB + b) * SS + s)) * DD;
        float4 a0 = *(const float4*)(row + d0);
        float4 a1 = *(const float4*)(row + d1);
        float p = a0.x * q0.x + a0.y * q0.y + a0.z * q0.z + a0.w * q0.w
                + a1.x * q1.x + a1.y * q1.y + a1.z * q1.z + a1.w * q1.w;
        p = wave_reduce_sum(p);
        const float a = p * sstat[b * SS + s];
        if (lane == 0) scores[b * NN + n] = a;
        if (a > m) {
            const float sc = (m == -INFINITY) ? 0.f : exp2f((m - a) * L2E);
            l *= sc;
            c0.x *= sc; c0.y *= sc; c0.z *= sc; c0.w *= sc;
            c1.x *= sc; c1.y *= sc; c1.z *= sc; c1.w *= sc;
            m = a;
        }
        const float e = exp2f((a - m) * L2E);
        l += e;
        c0.x += e * a0.x; c0.y += e * a0.y; c0.z += e * a0.z; c0.w += e * a0.w;
        c1.x += e * a1.x; c1.y += e * a1.y; c1.z += e * a1.z; c1.w += e * a1.w;
    }

    // intra-block combine of the 4 wave partials
    __shared__ float s_m[WPB], s_l[WPB];
    __shared__ float s_c[WPB][DD];
    *(float4*)(&s_c[wave][d0]) = c0;
    *(float4*)(&s_c[wave][d1]) = c1;
    if (lane == 0) { s_m[wave] = m; s_l[wave] = l; }
    __syncthreads();
    const float mb = fmaxf(fmaxf(s_m[0], s_m[1]), fmaxf(s_m[2], s_m[3]));
    float lb = 0.f, cA = 0.f, cB = 0.f;
    #pragma unroll
    for (int wv = 0; wv < WPB; ++wv) {
        const float mi = s_m[wv];
        const float sc = (mi == -INFINITY) ? 0.f : exp2f((mi - mb) * L2E);
        lb += s_l[wv] * sc;
        cA += s_c[wv][t] * sc;
        cB += s_c[wv][t + 256] * sc;
    }
    const int pidx = b * NBLK + chunk;
    part_c[(size_t)pidx * DD + t] = cA;
    part_c[(size_t)pidx * DD + t + 256] = cB;
    if (t == 0) { part_ml[pidx * 2] = mb; part_ml[pidx * 2 + 1] = lb; }
}

// ---------------------------------------------------------------------------
// K_POST: one block per batch b. Fuses partial-reduce + align finalize +
// attn_h. c_final and m/Z never touch global memory.
// ---------------------------------------------------------------------------
__global__ __launch_bounds__(256) void k_post(const float* __restrict__ part_c,
                                              const float* __restrict__ part_ml,
                                              const int* __restrict__ wl,
                                              const float* __restrict__ src,
                                              const float* __restrict__ Wout,
                                              float* __restrict__ out) {
    __shared__ float xs[2 * DD];     // concat(c_final, source)
    const int b = blockIdx.x, t = threadIdx.x;

    // global max over the 20 chunk partials (redundant per thread, L1-hot)
    float mg = -INFINITY;
    #pragma unroll
    for (int i = 0; i < NBLK; ++i) mg = fmaxf(mg, part_ml[(b * NBLK + i) * 2]);
    float Z = 0.f, cA = 0.f, cB = 0.f;
    for (int i = 0; i < NBLK; ++i) {
        const float mi = part_ml[(b * NBLK + i) * 2];
        const float li = part_ml[(b * NBLK + i) * 2 + 1];
        const float sc = (mi == -INFINITY) ? 0.f : exp2f((mi - mg) * L2E);
        Z += li * sc;
        cA += part_c[(size_t)(b * NBLK + i) * DD + t] * sc;
        cB += part_c[(size_t)(b * NBLK + i) * DD + t + 256] * sc;
    }
    const float invZ = 1.0f / Z;     // Z>0: every sentence has >=1 valid word
    xs[t] = cA * invZ;
    xs[t + 256] = cB * invZ;
    xs[DD + t] = src[b * DD + t];
    xs[DD + t + 256] = src[b * DD + t + 256];
    __syncthreads();

    // finalize align_vectors in place over the raw-score region of d_out
    float* av = out + BB * DD + (size_t)b * NN;
    #pragma unroll
    for (int j = 0; j < NN / 256; ++j) {
        const int n = j * 256 + t;
        const int s = n >> 6, w = n & 63;
        float v = 1e-20f;
        if (w < wl[b * SS + s]) v = exp2f((av[n] - mg) * L2E) * invZ + 1e-20f;
        av[n] = v;
    }

    // attn_h[b,d] = tanh( concat(c,src) . W_out[d,:] ), d = t and t+256
    #pragma unroll
    for (int rep = 0; rep < 2; ++rep) {
        const int d = rep * 256 + t;
        const float* row = Wout + (size_t)d * (2 * DD);
        float acc = 0.f;
        for (int k = 0; k < 2 * DD; k += 4) {
            float4 x = *(const float4*)(xs + k);
            float4 w = *(const float4*)(row + k);
            acc += x.x * w.x + x.y * w.y + x.z * w.z + x.w * w.w;
        }
        out[b * DD + d] = tanhf(acc);
    }
}

// ---------------------------------------------------------------------------
extern "C" void kernel_launch(void* const* d_in, const int* in_sizes, int n_in,
                              void* d_out, int out_size, void* d_ws, size_t ws_size,
                              hipStream_t stream) {
    const float* src = (const float*)d_in[0];   // [B, D]
    const float* wb  = (const float*)d_in[1];   // [WML, B, S, D]
    const int*   wl  = (const int*)  d_in[2];   // [B, S]
    const float* sb  = (const float*)d_in[3];   // [S, B, D]
    /* d_in[4] = sent_lengths: unused by forward math */
    const float* sa  = (const float*)d_in[5];   // [B, S]
    const float* Ww  = (const float*)d_in[6];   // [D, D]
    const float* Wsn = (const float*)d_in[7];   // [D, D]
    const float* Wo  = (const float*)d_in[8];   // [D, 2D]
    float* out = (float*)d_out;                 // [B*D] attn_h, then [B*N] align

    float* ws = (float*)d_ws;
    float* qw      = ws;                        // 32768
    float* sstat   = ws + 32768;                // 2560
    float* part_c  = ws + 35328;                // 64*20*512 = 655360
    float* part_ml = ws + 690688;               // 64*20*2   = 2560   (end ~2.8 MB)

    float* scores = out + BB * DD;              // raw scores live in the align slot

    hipLaunchKernelGGL(k_pre,  dim3(BB),       dim3(256), 0, stream, src, Ww, Wsn, sb, sa, qw, sstat);
    hipLaunchKernelGGL(k_main, dim3(NBLK, BB), dim3(256), 0, stream, wb, qw, sstat, wl,
                       scores, part_c, part_ml);
    hipLaunchKernelGGL(k_post, dim3(BB),       dim3(256), 0, stream, part_c, part_ml, wl, src, Wo, out);
}

// Round 4
// 557.634 us; speedup vs baseline: 1.0405x; 1.0342x over previous
//
#include <hip/hip_runtime.h>
#include <math.h>

// Problem constants (HierarchicalAttention: WML=64, B=64, S=40, D=512)
#define BB   64
#define SS   40
#define WMLC 64
#define DD   512
#define NN   2560           // S*WML
#define NBLK 20             // chunks (blocks) per batch for the main pass
#define WPB  4              // waves per block
#define NWAVES (NBLK*WPB)   // 80 waves per batch
#define RPW (NN/NWAVES)     // 32 rows per wave
#define L2E 1.4426950408889634f

__device__ __forceinline__ float wave_reduce_sum(float v) {
    #pragma unroll
    for (int off = 32; off > 0; off >>= 1) v += __shfl_xor(v, off, 64);
    return v;
}

// ---------------------------------------------------------------------------
// K1: q = source @ W^T, coalesced wave-per-dot form.
// grid (2, B): x=0 -> W_word/qw, x=1 -> W_sent/qs. 4 waves/block; wave wv
// computes outputs d = wv*128 + j. Lane keeps xs[lane*8..+7] in registers;
// each W row (2KB) is streamed with two perfectly-coalesced float4 loads
// (full 128B-line utilization in one instruction — no L1-reuse dependence),
// then a 6-step butterfly reduce. j-iterations are independent -> deep MLP.
// ---------------------------------------------------------------------------
__global__ __launch_bounds__(256) void k_proj(const float* __restrict__ src,
                                              const float* __restrict__ Ww,
                                              const float* __restrict__ Ws,
                                              float* __restrict__ qw,
                                              float* __restrict__ qs) {
    __shared__ float xs[DD];
    const int b = blockIdx.y;
    const int t = threadIdx.x, wave = t >> 6, lane = t & 63;
    const float* W = blockIdx.x ? Ws : Ww;
    float* q = blockIdx.x ? qs : qw;
    ((float2*)xs)[t] = ((const float2*)(src + b * DD))[t];
    __syncthreads();
    const float4 x0 = *(const float4*)(xs + lane * 8);
    const float4 x1 = *(const float4*)(xs + lane * 8 + 4);
    #pragma unroll 4
    for (int j = 0; j < DD / WPB; ++j) {
        const int d = wave * (DD / WPB) + j;
        const float* row = W + (size_t)d * DD + lane * 8;
        const float4 w0 = *(const float4*)(row);
        const float4 w1 = *(const float4*)(row + 4);
        float p = x0.x * w0.x + x0.y * w0.y + x0.z * w0.z + x0.w * w0.w
                + x1.x * w1.x + x1.y * w1.y + x1.z * w1.z + x1.w * w1.w;
        p = wave_reduce_sum(p);
        if (lane == 0) q[b * DD + d] = p;
    }
}

// ---------------------------------------------------------------------------
// K2: sstat[b,s] = dot(q_s[b,:], sent_bank[s,b,:]) * static_attn[b,s]
// grid (B), 4 waves, each wave does 10 sentences.
// ---------------------------------------------------------------------------
__global__ __launch_bounds__(256) void k_sstat(const float* __restrict__ qs,
                                               const float* __restrict__ sb,
                                               const float* __restrict__ sa,
                                               float* __restrict__ sstat) {
    const int b = blockIdx.x;
    const int t = threadIdx.x, wave = t >> 6, lane = t & 63;
    const int d0 = lane * 4, d1 = 256 + lane * 4;
    const float4 q0 = *(const float4*)(qs + b * DD + d0);
    const float4 q1 = *(const float4*)(qs + b * DD + d1);
    for (int j = 0; j < SS / WPB; ++j) {
        const int s = wave * (SS / WPB) + j;
        const float* row = sb + ((size_t)s * BB + b) * DD;
        float4 a0 = *(const float4*)(row + d0);
        float4 a1 = *(const float4*)(row + d1);
        float p = a0.x * q0.x + a0.y * q0.y + a0.z * q0.z + a0.w * q0.w
                + a1.x * q1.x + a1.y * q1.y + a1.z * q1.z + a1.w * q1.w;
        p = wave_reduce_sum(p);
        if (lane == 0) sstat[b * SS + s] = p * sa[b * SS + s];
    }
}

// ---------------------------------------------------------------------------
// K3 (main, HBM-bound): R0's proven streaming pass over VALID rows of
// word_bank only. One wave owns rows n = gw + 80k (k<32) of batch b.
// Masked rows skipped entirely (wave-uniform continue, no load issued).
// Raw scores go straight into the d_out align region (finalized by K5).
// ---------------------------------------------------------------------------
__global__ __launch_bounds__(256) void k_main(const float* __restrict__ wb,
                                              const float* __restrict__ qw,
                                              const float* __restrict__ sstat,
                                              const int* __restrict__ wl,
                                              float* __restrict__ scores,
                                              float* __restrict__ part_c,
                                              float* __restrict__ part_ml) {
    const int b = blockIdx.y;
    const int chunk = blockIdx.x;
    const int t = threadIdx.x, wave = t >> 6, lane = t & 63;
    const int gw = chunk * WPB + wave;               // 0..79
    const int d0 = lane * 4, d1 = 256 + lane * 4;
    const float4 q0 = *(const float4*)(qw + b * DD + d0);
    const float4 q1 = *(const float4*)(qw + b * DD + d1);

    float m = -INFINITY, l = 0.f;
    float4 c0 = {0.f, 0.f, 0.f, 0.f}, c1 = {0.f, 0.f, 0.f, 0.f};

    for (int k = 0; k < RPW; ++k) {
        const int n = gw + k * NWAVES;
        const int s = n >> 6, w = n & 63;
        if (w >= wl[b * SS + s]) continue;           // wave-uniform skip
        const float* row = wb + (size_t)(((w * BB + b) * SS + s)) * DD;
        float4 a0 = *(const float4*)(row + d0);
        float4 a1 = *(const float4*)(row + d1);
        float p = a0.x * q0.x + a0.y * q0.y + a0.z * q0.z + a0.w * q0.w
                + a1.x * q1.x + a1.y * q1.y + a1.z * q1.z + a1.w * q1.w;
        p = wave_reduce_sum(p);
        const float a = p * sstat[b * SS + s];
        if (lane == 0) scores[b * NN + n] = a;
        if (a > m) {
            const float sc = (m == -INFINITY) ? 0.f : exp2f((m - a) * L2E);
            l *= sc;
            c0.x *= sc; c0.y *= sc; c0.z *= sc; c0.w *= sc;
            c1.x *= sc; c1.y *= sc; c1.z *= sc; c1.w *= sc;
            m = a;
        }
        const float e = exp2f((a - m) * L2E);
        l += e;
        c0.x += e * a0.x; c0.y += e * a0.y; c0.z += e * a0.z; c0.w += e * a0.w;
        c1.x += e * a1.x; c1.y += e * a1.y; c1.z += e * a1.z; c1.w += e * a1.w;
    }

    // intra-block combine of the 4 wave partials
    __shared__ float s_m[WPB], s_l[WPB];
    __shared__ float s_c[WPB][DD];
    *(float4*)(&s_c[wave][d0]) = c0;
    *(float4*)(&s_c[wave][d1]) = c1;
    if (lane == 0) { s_m[wave] = m; s_l[wave] = l; }
    __syncthreads();
    const float mb = fmaxf(fmaxf(s_m[0], s_m[1]), fmaxf(s_m[2], s_m[3]));
    float lb = 0.f, cA = 0.f, cB = 0.f;
    #pragma unroll
    for (int wv = 0; wv < WPB; ++wv) {
        const float mi = s_m[wv];
        const float sc = (mi == -INFINITY) ? 0.f : exp2f((mi - mb) * L2E);
        lb += s_l[wv] * sc;
        cA += s_c[wv][t] * sc;
        cB += s_c[wv][t + 256] * sc;
    }
    const int pidx = b * NBLK + chunk;
    part_c[(size_t)pidx * DD + t] = cA;
    part_c[(size_t)pidx * DD + t + 256] = cB;
    if (t == 0) { part_ml[pidx * 2] = mb; part_ml[pidx * 2 + 1] = lb; }
}

// ---------------------------------------------------------------------------
// K4: per-batch reduction of the NBLK partials -> c_final[b,:], m_g, 1/Z
// ---------------------------------------------------------------------------
__global__ __launch_bounds__(256) void k_reduce(const float* __restrict__ part_c,
                                                const float* __restrict__ part_ml,
                                                float* __restrict__ c_final,
                                                float* __restrict__ mz) {
    const int b = blockIdx.x, t = threadIdx.x;
    float mg = -INFINITY;
    for (int i = 0; i < NBLK; ++i) mg = fmaxf(mg, part_ml[(b * NBLK + i) * 2]);
    float Z = 0.f, cA = 0.f, cB = 0.f;
    for (int i = 0; i < NBLK; ++i) {
        const float mi = part_ml[(b * NBLK + i) * 2];
        const float li = part_ml[(b * NBLK + i) * 2 + 1];
        const float sc = (mi == -INFINITY) ? 0.f : exp2f((mi - mg) * L2E);
        Z += li * sc;
        cA += part_c[(size_t)(b * NBLK + i) * DD + t] * sc;
        cB += part_c[(size_t)(b * NBLK + i) * DD + t + 256] * sc;
    }
    const float invZ = 1.0f / Z;   // Z>0: every sentence has >=1 valid word
    c_final[b * DD + t] = cA * invZ;
    c_final[b * DD + t + 256] = cB * invZ;
    if (t == 0) { mz[b * 2] = mg; mz[b * 2 + 1] = invZ; }
}

// ---------------------------------------------------------------------------
// K5: finalize align_vectors IN PLACE over the raw-score region of d_out:
// valid -> exp(a - m_g)/Z + 1e-20 ; masked -> 1e-20 exactly.
// grid (NN/256, B)
// ---------------------------------------------------------------------------
__global__ __launch_bounds__(256) void k_align(const int* __restrict__ wl,
                                               const float* __restrict__ mz,
                                               float* __restrict__ av) {
    const int b = blockIdx.y;
    const int n = blockIdx.x * 256 + threadIdx.x;
    const int s = n >> 6, w = n & 63;
    const int len = wl[b * SS + s];
    float v = 1e-20f;
    if (w < len) {
        const float a = av[b * NN + n];
        v = exp2f((a - mz[b * 2]) * L2E) * mz[b * 2 + 1] + 1e-20f;
    }
    av[b * NN + n] = v;
}

// ---------------------------------------------------------------------------
// K6: attn_h[b,d] = tanh( sum_k concat(c,source)[b,k] * W_out[d,k] )
// grid (2, B): thread handles one output d = x*256 + t.
// ---------------------------------------------------------------------------
__global__ __launch_bounds__(256) void k_attnh(const float* __restrict__ c_final,
                                               const float* __restrict__ src,
                                               const float* __restrict__ Wout,
                                               float* __restrict__ out) {
    __shared__ float xs[2 * DD];
    const int b = blockIdx.y, t = threadIdx.x;
    ((float2*)xs)[t] = ((const float2*)(c_final + b * DD))[t];
    ((float2*)(xs + DD))[t] = ((const float2*)(src + b * DD))[t];
    __syncthreads();
    const int d = blockIdx.x * 256 + t;
    const float* row = Wout + (size_t)d * (2 * DD);
    float acc = 0.f;
    for (int k = 0; k < 2 * DD; k += 4) {
        float4 x = *(const float4*)(xs + k);
        float4 w = *(const float4*)(row + k);
        acc += x.x * w.x + x.y * w.y + x.z * w.z + x.w * w.w;
    }
    out[b * DD + d] = tanhf(acc);
}

// ---------------------------------------------------------------------------
extern "C" void kernel_launch(void* const* d_in, const int* in_sizes, int n_in,
                              void* d_out, int out_size, void* d_ws, size_t ws_size,
                              hipStream_t stream) {
    const float* src = (const float*)d_in[0];   // [B, D]
    const float* wb  = (const float*)d_in[1];   // [WML, B, S, D]
    const int*   wl  = (const int*)  d_in[2];   // [B, S]
    const float* sb  = (const float*)d_in[3];   // [S, B, D]
    /* d_in[4] = sent_lengths: unused by forward math */
    const float* sa  = (const float*)d_in[5];   // [B, S]
    const float* Ww  = (const float*)d_in[6];   // [D, D]
    const float* Wsn = (const float*)d_in[7];   // [D, D]
    const float* Wo  = (const float*)d_in[8];   // [D, 2D]
    float* out = (float*)d_out;                 // [B*D] attn_h, then [B*N] align

    float* ws = (float*)d_ws;
    float* qw      = ws;                        // 32768
    float* qs      = ws + 32768;                // 32768
    float* sstat   = ws + 65536;                // 2560
    float* part_c  = ws + 68096;                // 64*20*512 = 655360
    float* part_ml = ws + 723456;               // 64*20*2   = 2560
    float* mz      = ws + 726016;               // 128
    float* c_final = ws + 726144;               // 32768  (end ~3.0 MB)

    float* scores = out + BB * DD;              // raw scores live in the align slot

    hipLaunchKernelGGL(k_proj,   dim3(2, BB),        dim3(256), 0, stream, src, Ww, Wsn, qw, qs);
    hipLaunchKernelGGL(k_sstat,  dim3(BB),           dim3(256), 0, stream, qs, sb, sa, sstat);
    hipLaunchKernelGGL(k_main,   dim3(NBLK, BB),     dim3(256), 0, stream, wb, qw, sstat, wl,
                       scores, part_c, part_ml);
    hipLaunchKernelGGL(k_reduce, dim3(BB),           dim3(256), 0, stream, part_c, part_ml, c_final, mz);
    hipLaunchKernelGGL(k_align,  dim3(NN / 256, BB), dim3(256), 0, stream, wl, mz, scores);
    hipLaunchKernelGGL(k_attnh,  dim3(2, BB),        dim3(256), 0, stream, c_final, src, Wo, out);
}